// Round 1
// baseline (391.072 us; speedup 1.0000x reference)
//
#include <hip/hip_runtime.h>

// SmartDerivatives R9: single-kernel rewrite — no LDS staging, no ws round-trip.
//
// R8 post-mortem: each z=left*x value is consumed exactly ONCE (ch 0-2 by the
// row-sum of atom i, ch 3-5 by the col-sum of atom j), so R8's 59KB LDS stage
// + 24,750 LDS lane-reads/frame was pure routing overhead behind a full-block
// barrier with only ~400/1024 threads computing. ~60us vs 22.7us HBM floor.
//
// R9: one block per frame, 8 waves; wave w owns rows {w, w+8, ...} (~21
// wave-iters each, +-7% balance). Rows are contiguous in memory: stream them
// as coalesced float2s (a float2 at even offset is always inside ONE
// descriptor -> one x gather via L1, two FMULs). Route in-register:
//   r==0: ch 0,1 -> per-lane row accumulators s0,s1
//   r==2: ch 2 -> s2; ch 3 -> ds_add acc[j*3+0]
//   r==4: ch 4,5 -> ds_add acc[j*3+1], acc[j*3+2]
// Per-row shuffle reduce of s0..s2 (levels skipped when row is short), then
// 3 ds_adds. Col ds_adds: stride-3 addresses across lanes -> <=2-way bank
// aliasing, no same-address lanes within an instruction. Epilogue squares and
// writes out directly. LDS = 1.2KB, VGPR-lean -> 32 waves/CU.

#define D_DESC  4950
#define BATCH   1024
#define NOUT    300
#define NWAVES  8      // 512 threads/block, one block per frame

__device__ __forceinline__ int rowstart(int i) { return (i * (199 - i)) >> 1; }

__global__ __launch_bounds__(512, 8)
void sd_kernel(const float* __restrict__ x,
               const float* __restrict__ left,
               float* __restrict__ out)
{
    __shared__ __align__(16) float acc[NOUT];

    const int b    = blockIdx.x;
    const int tid  = threadIdx.x;
    const int lane = tid & 63;
    const int w    = tid >> 6;

    if (tid < NOUT) acc[tid] = 0.0f;
    __syncthreads();

    const float* __restrict__ Lb = left + (size_t)b * (D_DESC * 6);
    const float* __restrict__ xb = x    + (size_t)b * D_DESC;

    for (int i = w; i < 99; i += NWAVES) {
        const int rs  = rowstart(i);
        const int len = 99 - i;          // descriptors in this row
        const int nf  = len * 6;         // floats in this row (even)
        const int n2  = nf >> 1;         // float2 count
        const float2* __restrict__ base2 = (const float2*)(Lb + rs * 6); // 8B-aligned
        const float*  __restrict__ xrow  = xb + rs;
        const int jb3 = (i + 1) * 3;     // acc offset of col j at dl=0

        float s0 = 0.f, s1 = 0.f, s2 = 0.f;

        // lane's first float offset g = 4*lane: dl = g/6, r = g%6 in {0,2,4};
        // per iter g += 256 = 6*42+4 -> incremental dl/r update, no div in loop.
        int dl = (lane << 2) / 6;
        int r  = (lane << 2) - 6 * dl;
        int p2 = lane << 1;

        const int niter = (n2 + 127) >> 7;   // ceil(nf/256)
        for (int m = 0; m < niter; ++m) {
            // pair A: floats g,g+1 = channels r,r+1 of descriptor dl
            if (p2 < n2) {
                const float2 L = base2[p2];
                const float xv = xrow[dl];
                const float za = L.x * xv;
                const float zb = L.y * xv;
                if (r == 0) {
                    s0 += za; s1 += zb;
                } else if (r == 2) {
                    s2 += za;
                    atomicAdd(&acc[jb3 + dl * 3 + 0], zb);
                } else {
                    atomicAdd(&acc[jb3 + dl * 3 + 1], za);
                    atomicAdd(&acc[jb3 + dl * 3 + 2], zb);
                }
            }
            // pair B: floats g+2,g+3 = channels r+2 (mod 6) of dl (or dl+1)
            if (p2 + 1 < n2) {
                const int dB = (r == 4) ? dl + 1 : dl;
                const int rB = (r == 4) ? 0 : r + 2;
                const float2 L = base2[p2 + 1];
                const float xv = xrow[dB];
                const float za = L.x * xv;
                const float zb = L.y * xv;
                if (rB == 0) {
                    s0 += za; s1 += zb;
                } else if (rB == 2) {
                    s2 += za;
                    atomicAdd(&acc[jb3 + dB * 3 + 0], zb);
                } else {
                    atomicAdd(&acc[jb3 + dB * 3 + 1], za);
                    atomicAdd(&acc[jb3 + dB * 3 + 2], zb);
                }
            }
            dl += (r >= 2) ? 43 : 42;
            r   = (r >= 2) ? r - 2 : r + 4;
            p2 += 128;
        }

        // wave-reduce the row-channel sums; skip levels where all source
        // lanes are provably zero (short rows).
        const int nact = (nf + 3) >> 2;      // lanes that held data
        #pragma unroll
        for (int off = 32; off >= 1; off >>= 1) {
            if (nact > off) {
                s0 += __shfl_down(s0, off);
                s1 += __shfl_down(s1, off);
                s2 += __shfl_down(s2, off);
            }
        }
        if (lane == 0) {
            atomicAdd(&acc[i * 3 + 0], s0);
            atomicAdd(&acc[i * 3 + 1], s1);
            atomicAdd(&acc[i * 3 + 2], s2);
        }
    }
    __syncthreads();

    // out[b, t] = acc[t]^2, float4-vectorized (300*4B = 75*16B, aligned)
    if (tid < NOUT / 4) {
        const float4 v = ((const float4*)acc)[tid];
        float4 o;
        o.x = v.x * v.x; o.y = v.y * v.y;
        o.z = v.z * v.z; o.w = v.w * v.w;
        ((float4*)(out + (size_t)b * NOUT))[tid] = o;
    }
}

extern "C" void kernel_launch(void* const* d_in, const int* in_sizes, int n_in,
                              void* d_out, int out_size, void* d_ws, size_t ws_size,
                              hipStream_t stream) {
    (void)in_sizes; (void)n_in; (void)d_ws; (void)ws_size; (void)out_size;
    const float* x    = (const float*)d_in[0];   // [BATCH, D]
    const float* left = (const float*)d_in[1];   // [BATCH*D*6]
    sd_kernel<<<BATCH, 512, 0, stream>>>(x, left, (float*)d_out);
}